// Round 2
// baseline (10.044 us; speedup 1.0000x reference)
//
#include <hip/hip_runtime.h>

// MaskNeighborSampler — 2 rows per 64-lane wave.
//
// Per wave (rows 2w, 2w+1):
//   4 independent random-row gathers in flight (adjA, tsA, adjB, tsB),
//   u load and both outputs are single fully-coalesced 4B/lane accesses
//   (lanes 0..31 = row A's 32 samples, lanes 32..63 = row B's).
//   count via __ballot + __popcll; sample values via __shfl (no re-gather).
//
// Output layout (single float32 buffer, tuple concatenated):
//   d_out[0 .. B*S)    = neighbors (ids < 2^24, exact in f32)
//   d_out[B*S .. 2BS)  = ts values

#define MAX_DEG 64
#define NSAMP   32

__global__ __launch_bounds__(256) void MaskNeighborSampler_kernel(
    const int* __restrict__ ids,
    const float* __restrict__ tss,
    const int* __restrict__ adj,
    const float* __restrict__ tsi,
    const float* __restrict__ u,
    float* __restrict__ out_nbr,
    float* __restrict__ out_ts,
    int B) {
  const int wave = (blockIdx.x * blockDim.x + threadIdx.x) >> 6;
  const int lane = threadIdx.x & 63;
  const int rowA = wave * 2;
  if (rowA >= B) return;
  const int rowB = (rowA + 1 < B) ? rowA + 1 : rowA;   // B=16384 (even); safe guard

  // wave-uniform scalars
  const int   idA = ids[rowA];
  const int   idB = ids[rowB];
  const float tA  = tss[rowA];
  const float tB  = tss[rowB];

  // 4 independent coalesced 256B row gathers (the latency-critical loads)
  const int offA = idA * MAX_DEG + lane;               // < 64M, fits int
  const int offB = idB * MAX_DEG + lane;
  const int   adjA = adj[offA];
  const int   adjB = adj[offB];
  const float tsA  = tsi[offA];
  const float tsB  = tsi[offB];

  // one coalesced u load covers both rows: lanes 0..31 -> A, 32..63 -> B
  const size_t obase = (size_t)rowA * NSAMP;           // contiguous 64 elems
  const float uu = u[obase + lane];

  // valid-prefix counts (strict f32 compare, full-wave ballot per row)
  const int cntA = __popcll(__ballot(tsA < tA));
  const int cntB = __popcll(__ballot(tsB < tB));
  const int errA = cntA > 0 ? cntA : 1;
  const int errB = cntB > 0 ? cntB : 1;

  const bool lo  = lane < NSAMP;
  const int  err = lo ? errA : errB;
  int col = (int)(uu * (float)err);                    // same IEEE mul+trunc as ref
  if (col > err - 1) col = err - 1;

  // fetch sampled values from the lane that already holds them
  const int   nA = __shfl(adjA, col, 64);
  const int   nB = __shfl(adjB, col, 64);
  const float vA = __shfl(tsA,  col, 64);
  const float vB = __shfl(tsB,  col, 64);

  const bool valid = lo ? (cntA > 0) : (cntB > 0);
  out_nbr[obase + lane] = valid ? (float)(lo ? nA : nB) : 0.0f;
  out_ts [obase + lane] = valid ? (lo ? vA : vB)        : 0.0f;
}

extern "C" void kernel_launch(void* const* d_in, const int* in_sizes, int n_in,
                              void* d_out, int out_size, void* d_ws, size_t ws_size,
                              hipStream_t stream) {
  const int*   ids = (const int*)  d_in[0];
  const float* tss = (const float*)d_in[1];
  const int*   adj = (const int*)  d_in[2];
  const float* tsi = (const float*)d_in[3];
  const float* u   = (const float*)d_in[4];
  const int B = in_sizes[0];

  float* out_nbr = (float*)d_out;
  float* out_ts  = out_nbr + (size_t)B * NSAMP;

  const int waves = (B + 1) / 2;                       // 2 rows per wave
  const int threads = 256;                             // 4 waves/block
  const int grid = (waves * 64 + threads - 1) / threads;
  MaskNeighborSampler_kernel<<<grid, threads, 0, stream>>>(
      ids, tss, adj, tsi, u, out_nbr, out_ts, B);
}